// Round 7
// baseline (7377.029 us; speedup 1.0000x reference)
//
#include <hip/hip_runtime.h>

typedef float f32x4  __attribute__((ext_vector_type(4)));
typedef float f32x16 __attribute__((ext_vector_type(16)));
typedef int   i32x4  __attribute__((ext_vector_type(4)));
typedef int   i32x8  __attribute__((ext_vector_type(8)));

#define T_DIM 8192
#define H_DIM 4096
#define SC1 0x7f7f7f7f   // e8m0 scale = 127 -> 2^0 = 1.0 in all 4 bytes

__device__ __forceinline__ unsigned int pack_fp8x4(float a, float b, float c, float d) {
    int v = __builtin_amdgcn_cvt_pk_fp8_f32(a, b, 0, false);
    v = __builtin_amdgcn_cvt_pk_fp8_f32(c, d, v, true);
    return (unsigned int)v;
}

// ---------------------------------------------------------------------------
// Global fp8 layout: PLAIN row-major [row][k] for both qx and wqT.
// A is reg-staged into LDS with XOR slot swizzle slot' = slot ^ ((row>>1)&3)
// applied on the GLOBAL source address (LDS image linear); ds_read applies the
// same XOR -> conflict-free b128. B is consumed DIRECT from global (L1/L2).
// ---------------------------------------------------------------------------

// w[l][k][n] f32  ->  wqT[l][n][k] fp8(e4m3), plain layout
__global__ __launch_bounds__(256) void wquant_kernel(
    const float* __restrict__ w, unsigned char* __restrict__ wqT)
{
    const int l  = blockIdx.z;
    const int n0 = blockIdx.x * 64;
    const int k0 = blockIdx.y * 64;
    const int tid = threadIdx.x;
    __shared__ unsigned char tile[64][68];   // [k][n]
    const float* wl = w + (size_t)l * H_DIM * H_DIM;
#pragma unroll
    for (int p = 0; p < 4; ++p) {
        int r = p * 16 + (tid >> 4);         // k within tile
        int c = (tid & 15) * 4;              // n within tile
        f32x4 v = *(const f32x4*)(wl + (size_t)(k0 + r) * H_DIM + n0 + c);
        *(unsigned int*)&tile[r][c] = pack_fp8x4(v[0], v[1], v[2], v[3]);
    }
    __syncthreads();
    const int nl = tid >> 2;                 // n within tile (output row)
    const int g  = tid & 3;                  // 16B chunk within 64B
    unsigned int words[4];
#pragma unroll
    for (int wi = 0; wi < 4; ++wi) {
        unsigned int a = 0;
#pragma unroll
        for (int b = 0; b < 4; ++b)
            a |= (unsigned int)tile[g * 16 + wi * 4 + b][nl] << (8 * b);
        words[wi] = a;
    }
    unsigned char* op = wqT + ((size_t)l * H_DIM + n0 + nl) * H_DIM + k0 + g * 16;
    uint4 ov; ov.x = words[0]; ov.y = words[1]; ov.z = words[2]; ov.w = words[3];
    *(uint4*)op = ov;
}

// ---------------- row-wise RMSNorm (+relu) (+quant) ----------------
template <int MODE>
__global__ __launch_bounds__(256) void row_kernel(
    const float* __restrict__ in,
    float* __restrict__ resid_out,
    void* __restrict__ out,
    const float* __restrict__ g,
    const float* __restrict__ scale_p)
{
    const int row = blockIdx.x;
    const int tid = threadIdx.x;
    const float* rin = in + (size_t)row * H_DIM;
    float x[16];
    float ss = 0.0f;
#pragma unroll
    for (int j = 0; j < 4; ++j) {
        const int base = (j * 256 + tid) * 4;
        f32x4 v = *(const f32x4*)(rin + base);
        f32x4 rv;
#pragma unroll
        for (int i = 0; i < 4; ++i) {
            float t = v[i];
            if (MODE == 0) t = fmaxf(t, 0.0f);
            x[j * 4 + i] = t;
            rv[i] = t;
            ss += t * t;
        }
        if (MODE == 0)
            *(f32x4*)(resid_out + (size_t)row * H_DIM + base) = rv;
    }
#pragma unroll
    for (int off = 32; off > 0; off >>= 1)
        ss += __shfl_down(ss, off, 64);
    __shared__ float red[4];
    if ((tid & 63) == 0) red[tid >> 6] = ss;
    __syncthreads();
    const float var  = (red[0] + red[1] + red[2] + red[3]) * (1.0f / (float)H_DIM);
    const float rinv = 1.0f / sqrtf(var + 1e-6f);

    if (MODE == 2) {
        float* ro = (float*)out + (size_t)row * H_DIM;
#pragma unroll
        for (int j = 0; j < 4; ++j) {
            const int base = (j * 256 + tid) * 4;
            f32x4 gv = *(const f32x4*)(g + base);
            f32x4 ov;
#pragma unroll
            for (int i = 0; i < 4; ++i) ov[i] = (x[j * 4 + i] * rinv) * gv[i];
            *(f32x4*)(ro + base) = ov;
        }
    } else {
        const float s = scale_p[0];
        unsigned int* qo = (unsigned int*)out + (size_t)row * (H_DIM / 4);
#pragma unroll
        for (int j = 0; j < 4; ++j) {
            const int base = (j * 256 + tid) * 4;
            f32x4 gv = *(const f32x4*)(g + base);
            float q[4];
#pragma unroll
            for (int i = 0; i < 4; ++i) {
                float y = (x[j * 4 + i] * rinv) * gv[i];
                y = y / s;
                q[i] = fminf(fmaxf(y, -448.0f), 448.0f);
            }
            qo[j * 256 + tid] = pack_fp8x4(q[0], q[1], q[2], q[3]);
        }
    }
}

// ---- MX-fp8 GEMM, 256x256 tile, BK=64, A reg-staged 2-buf LDS, B direct ----
#define LGKM0B do { asm volatile("s_waitcnt lgkmcnt(0)" ::: "memory"); \
                    __builtin_amdgcn_s_barrier(); } while (0)

#define MM2(m, P) do {                                                          \
    i32x8 f0_ = __builtin_shufflevector(b##P##0l, b##P##0h, 0,1,2,3,4,5,6,7);   \
    i32x8 f1_ = __builtin_shufflevector(b##P##1l, b##P##1h, 0,1,2,3,4,5,6,7);   \
    acc[m][0] = __builtin_amdgcn_mfma_scale_f32_32x32x64_f8f6f4(                \
        fa[m], f0_, acc[m][0], 0, 0, 0, SC1, 0, SC1);                           \
    acc[m][1] = __builtin_amdgcn_mfma_scale_f32_32x32x64_f8f6f4(                \
        fa[m], f1_, acc[m][1], 0, 0, 0, SC1, 0, SC1);                           \
} while (0)

#define RDA(ORQ, m) do {                                                        \
    *(i32x4*)&fa[m]         = *(const i32x4*)(lds + (ORQ) + wrA + (m) * 2048 + fo0); \
    *(((i32x4*)&fa[m]) + 1) = *(const i32x4*)(lds + (ORQ) + wrA + (m) * 2048 + fo1); \
} while (0)

// iter t: gload A(t+2)->LD regs, gload B(t+1)->FN regs, ds_write A(t+1)=WR
// regs -> buf BUF, fence+barrier, MFMA(t) with FC interleaved with ds_read of
// tile t+1 frags from BUF. All global-load waits are compiler-counted.
#define AITER(WRa, WRb, LDa, LDb, FC, FN, BUF) do {                             \
    LDa = *(const i32x4*)(gAlo + kt2);                                          \
    LDb = *(const i32x4*)(gAhi + kt2);                                          \
    kt2 += 64;                                                                  \
    b##FN##0l = *(const i32x4*)(gB0 + ktb);                                     \
    b##FN##0h = *(const i32x4*)(gB0 + ktb + 16);                                \
    b##FN##1l = *(const i32x4*)(gB1 + ktb);                                     \
    b##FN##1h = *(const i32x4*)(gB1 + ktb + 16);                                \
    ktb += 64;                                                                  \
    *(i32x4*)(lds + (BUF) + tid16)        = WRa;                                \
    *(i32x4*)(lds + (BUF) + 8192 + tid16) = WRb;                                \
    LGKM0B;                                                                     \
    __builtin_amdgcn_s_setprio(1); MM2(0, FC); MM2(1, FC);                      \
    __builtin_amdgcn_s_setprio(0);                                              \
    RDA(BUF, 0); RDA(BUF, 1);                                                   \
    __builtin_amdgcn_s_setprio(1); MM2(2, FC); MM2(3, FC);                      \
    __builtin_amdgcn_s_setprio(0);                                              \
    RDA(BUF, 2); RDA(BUF, 3);                                                   \
} while (0)

__global__ __launch_bounds__(512, 4) void gemm_fp8_kernel(
    const unsigned char* __restrict__ A,
    const unsigned char* __restrict__ B,
    float* __restrict__ C,
    const float* __restrict__ s_in,
    const float* __restrict__ s_w)
{
    __shared__ unsigned char lds[32768];   // 2 bufs x 16K (A only)

    const float alpha = s_in[0] * s_w[0];

    // XCD-bijective swizzle (512 blocks = 64/XCD) + 8x8 supertile per XCD
    const int b = blockIdx.x;
    const int local = b >> 3, chunk = b & 7;         // chunk = XCD id
    const int bm = (chunk & 3) * 8 + (local & 7);    // M/256 = 32
    const int bn = (chunk >> 2) * 8 + (local >> 3);  // N/256 = 16

    const int tid  = threadIdx.x;
    const int wave = tid >> 6;
    const int lane = tid & 63;
    const int wr   = wave >> 2;   // 2 M-waves
    const int wc   = wave & 3;    // 4 N-waves

    // A frag ds_read: row=(lane&31), slot=(lane>>5)*2+h, stored^((row>>1)&3)
    const int sw  = (lane >> 1) & 3;
    const int fo0 = (lane & 31) * 64 + ((((lane >> 5) * 2) + 0 ^ sw)) * 16;
    const int fo1 = (lane & 31) * 64 + ((((lane >> 5) * 2) + 1 ^ sw)) * 16;
    const int wrA = wr * 8192;            // A region: 128 rows per wr

    // A staging: thread tid covers LDS [row=tid>>2][slot=tid&3]; global XOR'd
    const int voff = (tid >> 2) * H_DIM + ((tid & 3) ^ ((tid >> 3) & 3)) * 16;
    const unsigned char* gAlo = A + (size_t)bm * 256 * H_DIM + voff;
    const unsigned char* gAhi = gAlo + (size_t)128 * H_DIM;
    const int tid16 = tid * 16;

    // B direct: lane reads row (wc*64 + n*32 + (lane&31)), k=(lane>>5)*32+[0,32)
    const unsigned char* gB0 =
        B + ((size_t)(bn * 256 + wc * 64 + (lane & 31))) * H_DIM + ((lane >> 5) * 32);
    const unsigned char* gB1 = gB0 + (size_t)32 * H_DIM;

    f32x16 acc[4][2];
#pragma unroll
    for (int m = 0; m < 4; ++m)
#pragma unroll
        for (int n = 0; n < 2; ++n)
#pragma unroll
            for (int e = 0; e < 16; ++e) acc[m][n][e] = 0.0f;

    i32x8 fa[4];
    i32x4 rXa, rXb, rYa, rYb;
    i32x4 bX0l, bX0h, bX1l, bX1h, bY0l, bY0h, bY1l, bY1h;
    int kt2, ktb;

    // prologue: A(0)->rX, B(0)->fbX, A(1)->rY; write A(0)->buf0; read frags
    rXa = *(const i32x4*)(gAlo);
    rXb = *(const i32x4*)(gAhi);
    bX0l = *(const i32x4*)(gB0);      bX0h = *(const i32x4*)(gB0 + 16);
    bX1l = *(const i32x4*)(gB1);      bX1h = *(const i32x4*)(gB1 + 16);
    rYa = *(const i32x4*)(gAlo + 64);
    rYb = *(const i32x4*)(gAhi + 64);
    *(i32x4*)(lds + tid16)        = rXa;
    *(i32x4*)(lds + 8192 + tid16) = rXb;
    LGKM0B;
    RDA(0, 0); RDA(0, 1); RDA(0, 2); RDA(0, 3);
    kt2 = 128;   // next A gload: tile 2
    ktb = 64;    // next B gload: tile 1

    // t = 0..61 (31 x 2-unrolled); buf(t+1): t even -> 16384, t odd -> 0
#pragma unroll 1
    for (int it = 0; it < 31; ++it) {
        AITER(rYa, rYb, rXa, rXb, X, Y, 16384);   // even t
        AITER(rXa, rXb, rYa, rYb, Y, X, 0);       // odd t
    }
    // t = 62: write A(63)=rY -> buf1; load B(63)->fbY; compute tile62 (fbX)
    bY0l = *(const i32x4*)(gB0 + ktb);  bY0h = *(const i32x4*)(gB0 + ktb + 16);
    bY1l = *(const i32x4*)(gB1 + ktb);  bY1h = *(const i32x4*)(gB1 + ktb + 16);
    *(i32x4*)(lds + 16384 + tid16)        = rYa;
    *(i32x4*)(lds + 16384 + 8192 + tid16) = rYb;
    LGKM0B;
    __builtin_amdgcn_s_setprio(1); MM2(0, X); MM2(1, X);
    __builtin_amdgcn_s_setprio(0);
    RDA(16384, 0); RDA(16384, 1);
    __builtin_amdgcn_s_setprio(1); MM2(2, X); MM2(3, X);
    __builtin_amdgcn_s_setprio(0);
    RDA(16384, 2); RDA(16384, 3);
    // t = 63
    MM2(0, Y); MM2(1, Y); MM2(2, Y); MM2(3, Y);

    // epilogue: C += acc*alpha
    // (32x32 C/D: col = lane&31, row = (e&3) + 8*(e>>2) + 4*(lane>>5))
    const int lrow0 = bm * 256 + wr * 128 + 4 * (lane >> 5);
    const int lcol0 = bn * 256 + wc * 64 + (lane & 31);
#pragma unroll
    for (int m = 0; m < 4; ++m) {
#pragma unroll
        for (int n = 0; n < 2; ++n) {
#pragma unroll
            for (int e = 0; e < 16; ++e) {
                const int row = lrow0 + m * 32 + (e & 3) + 8 * (e >> 2);
                float* cp = C + (size_t)row * H_DIM + lcol0 + n * 32;
                *cp = acc[m][n][e] * alpha + *cp;
            }
        }
    }
}

extern "C" void kernel_launch(void* const* d_in, const int* in_sizes, int n_in,
                              void* d_out, int out_size, void* d_ws, size_t ws_size,
                              hipStream_t stream) {
    const float* h   = (const float*)d_in[0];   // [8192,4096]
    const float* nw  = (const float*)d_in[1];   // [4,4096]
    const float* w   = (const float*)d_in[2];   // [3,4096,4096]
    const float* wsc = (const float*)d_in[3];   // [3]
    const float* sc  = (const float*)d_in[4];   // [3]
    float* out = (float*)d_out;

    unsigned char* wqT = (unsigned char*)d_ws;                       // 3*16M fp8
    unsigned char* qx  = wqT + (size_t)3 * H_DIM * H_DIM;            // 33.5M fp8
    float* resid = (float*)(qx + (size_t)T_DIM * H_DIM);             // 134M f32

    const size_t WSTRIDE = (size_t)H_DIM * H_DIM;

    wquant_kernel<<<dim3(64, 64, 3), 256, 0, stream>>>(w, wqT);

    row_kernel<0><<<T_DIM, 256, 0, stream>>>(h, resid, qx, nw + 0 * H_DIM, sc + 0);
    gemm_fp8_kernel<<<512, 512, 0, stream>>>(qx, wqT + 0 * WSTRIDE, resid, sc + 0, wsc + 0);

    row_kernel<1><<<T_DIM, 256, 0, stream>>>(resid, nullptr, qx, nw + 1 * H_DIM, sc + 1);
    gemm_fp8_kernel<<<512, 512, 0, stream>>>(qx, wqT + 1 * WSTRIDE, resid, sc + 1, wsc + 1);

    row_kernel<1><<<T_DIM, 256, 0, stream>>>(resid, nullptr, qx, nw + 2 * H_DIM, sc + 2);
    gemm_fp8_kernel<<<512, 512, 0, stream>>>(qx, wqT + 2 * WSTRIDE, resid, sc + 2, wsc + 2);

    row_kernel<2><<<T_DIM, 256, 0, stream>>>(resid, nullptr, out, nw + 3 * H_DIM, nullptr);
}

// Round 8
// 812.327 us; speedup vs baseline: 9.0814x; 9.0814x over previous
//
#include <hip/hip_runtime.h>

typedef float f32x4  __attribute__((ext_vector_type(4)));
typedef float f32x16 __attribute__((ext_vector_type(16)));
typedef int   i32x4  __attribute__((ext_vector_type(4)));
typedef int   i32x8  __attribute__((ext_vector_type(8)));

#define T_DIM 8192
#define H_DIM 4096
#define SC1 0x7f7f7f7f   // e8m0 scale = 127 -> 2^0 = 1.0 in all 4 bytes

__device__ __forceinline__ unsigned int pack_fp8x4(float a, float b, float c, float d) {
    int v = __builtin_amdgcn_cvt_pk_fp8_f32(a, b, 0, false);
    v = __builtin_amdgcn_cvt_pk_fp8_f32(c, d, v, true);
    return (unsigned int)v;
}

// ---------------------------------------------------------------------------
// Global fp8 layout: PLAIN row-major [row][k] for both qx and wqT.
// A is reg-staged into LDS with XOR slot swizzle slot' = slot ^ ((row>>1)&3)
// applied on the GLOBAL source address (LDS image linear); ds_read applies the
// same XOR -> conflict-free b128. B is consumed DIRECT from global (L1/L2).
// ---------------------------------------------------------------------------

// w[l][k][n] f32  ->  wqT[l][n][k] fp8(e4m3), plain layout
__global__ __launch_bounds__(256) void wquant_kernel(
    const float* __restrict__ w, unsigned char* __restrict__ wqT)
{
    const int l  = blockIdx.z;
    const int n0 = blockIdx.x * 64;
    const int k0 = blockIdx.y * 64;
    const int tid = threadIdx.x;
    __shared__ unsigned char tile[64][68];   // [k][n]
    const float* wl = w + (size_t)l * H_DIM * H_DIM;
#pragma unroll
    for (int p = 0; p < 4; ++p) {
        int r = p * 16 + (tid >> 4);         // k within tile
        int c = (tid & 15) * 4;              // n within tile
        f32x4 v = *(const f32x4*)(wl + (size_t)(k0 + r) * H_DIM + n0 + c);
        *(unsigned int*)&tile[r][c] = pack_fp8x4(v[0], v[1], v[2], v[3]);
    }
    __syncthreads();
    const int nl = tid >> 2;                 // n within tile (output row)
    const int g  = tid & 3;                  // 16B chunk within 64B
    unsigned int words[4];
#pragma unroll
    for (int wi = 0; wi < 4; ++wi) {
        unsigned int a = 0;
#pragma unroll
        for (int b = 0; b < 4; ++b)
            a |= (unsigned int)tile[g * 16 + wi * 4 + b][nl] << (8 * b);
        words[wi] = a;
    }
    unsigned char* op = wqT + ((size_t)l * H_DIM + n0 + nl) * H_DIM + k0 + g * 16;
    uint4 ov; ov.x = words[0]; ov.y = words[1]; ov.z = words[2]; ov.w = words[3];
    *(uint4*)op = ov;
}

// ---------------- row-wise RMSNorm (+relu) (+quant) ----------------
template <int MODE>
__global__ __launch_bounds__(256) void row_kernel(
    const float* __restrict__ in,
    float* __restrict__ resid_out,
    void* __restrict__ out,
    const float* __restrict__ g,
    const float* __restrict__ scale_p)
{
    const int row = blockIdx.x;
    const int tid = threadIdx.x;
    const float* rin = in + (size_t)row * H_DIM;
    float x[16];
    float ss = 0.0f;
#pragma unroll
    for (int j = 0; j < 4; ++j) {
        const int base = (j * 256 + tid) * 4;
        f32x4 v = *(const f32x4*)(rin + base);
        f32x4 rv;
#pragma unroll
        for (int i = 0; i < 4; ++i) {
            float t = v[i];
            if (MODE == 0) t = fmaxf(t, 0.0f);
            x[j * 4 + i] = t;
            rv[i] = t;
            ss += t * t;
        }
        if (MODE == 0)
            *(f32x4*)(resid_out + (size_t)row * H_DIM + base) = rv;
    }
#pragma unroll
    for (int off = 32; off > 0; off >>= 1)
        ss += __shfl_down(ss, off, 64);
    __shared__ float red[4];
    if ((tid & 63) == 0) red[tid >> 6] = ss;
    __syncthreads();
    const float var  = (red[0] + red[1] + red[2] + red[3]) * (1.0f / (float)H_DIM);
    const float rinv = 1.0f / sqrtf(var + 1e-6f);

    if (MODE == 2) {
        float* ro = (float*)out + (size_t)row * H_DIM;
#pragma unroll
        for (int j = 0; j < 4; ++j) {
            const int base = (j * 256 + tid) * 4;
            f32x4 gv = *(const f32x4*)(g + base);
            f32x4 ov;
#pragma unroll
            for (int i = 0; i < 4; ++i) ov[i] = (x[j * 4 + i] * rinv) * gv[i];
            *(f32x4*)(ro + base) = ov;
        }
    } else {
        const float s = scale_p[0];
        unsigned int* qo = (unsigned int*)out + (size_t)row * (H_DIM / 4);
#pragma unroll
        for (int j = 0; j < 4; ++j) {
            const int base = (j * 256 + tid) * 4;
            f32x4 gv = *(const f32x4*)(g + base);
            float q[4];
#pragma unroll
            for (int i = 0; i < 4; ++i) {
                float y = (x[j * 4 + i] * rinv) * gv[i];
                y = y / s;
                q[i] = fminf(fmaxf(y, -448.0f), 448.0f);
            }
            qo[j * 256 + tid] = pack_fp8x4(q[0], q[1], q[2], q[3]);
        }
    }
}

// ---- MX-fp8 GEMM, 256x256 tile, BK=64, A reg-staged 2-buf LDS, B direct ----
#define LGKM0B do { asm volatile("s_waitcnt lgkmcnt(0)" ::: "memory"); \
                    __builtin_amdgcn_s_barrier(); } while (0)

#define MM2(m, P) do {                                                          \
    acc[m][0] = __builtin_amdgcn_mfma_scale_f32_32x32x64_f8f6f4(                \
        fa[m], b##P##0, acc[m][0], 0, 0, 0, SC1, 0, SC1);                       \
    acc[m][1] = __builtin_amdgcn_mfma_scale_f32_32x32x64_f8f6f4(                \
        fa[m], b##P##1, acc[m][1], 0, 0, 0, SC1, 0, SC1);                       \
} while (0)

#define RDA(ORQ, m) do {                                                        \
    *(i32x4*)&fa[m]         = *(const i32x4*)(lds + (ORQ) + wrA + (m) * 2048 + fo0); \
    *(((i32x4*)&fa[m]) + 1) = *(const i32x4*)(lds + (ORQ) + wrA + (m) * 2048 + fo1); \
} while (0)

// iter t: gload A(t+2)->LD regs, gload B(t+1)->FN regs, ds_write A(t+1)=WR
// regs -> buf BUF, fence+barrier, MFMA(t) with FC interleaved with ds_read of
// tile t+1 frags from BUF. All global-load waits are compiler-counted.
#define AITER(WRa, WRb, LDa, LDb, FC, FN, BUF) do {                             \
    LDa = *(const i32x4*)(gAlo + kt2);                                          \
    LDb = *(const i32x4*)(gAhi + kt2);                                          \
    kt2 += 64;                                                                  \
    b##FN##0 = *(const i32x8*)(gB0 + ktb);                                      \
    b##FN##1 = *(const i32x8*)(gB1 + ktb);                                      \
    ktb += 64;                                                                  \
    *(i32x4*)(lds + (BUF) + tid16)        = WRa;                                \
    *(i32x4*)(lds + (BUF) + 8192 + tid16) = WRb;                                \
    LGKM0B;                                                                     \
    __builtin_amdgcn_s_setprio(1); MM2(0, FC); MM2(1, FC);                      \
    __builtin_amdgcn_s_setprio(0);                                              \
    RDA(BUF, 0); RDA(BUF, 1);                                                   \
    __builtin_amdgcn_s_setprio(1); MM2(2, FC); MM2(3, FC);                      \
    __builtin_amdgcn_s_setprio(0);                                              \
    RDA(BUF, 2); RDA(BUF, 3);                                                   \
} while (0)

__global__ __launch_bounds__(512, 2) void gemm_fp8_kernel(
    const unsigned char* __restrict__ A,
    const unsigned char* __restrict__ B,
    float* __restrict__ C,
    const float* __restrict__ s_in,
    const float* __restrict__ s_w)
{
    __shared__ unsigned char lds[32768];   // 2 bufs x 16K (A only)

    const float alpha = s_in[0] * s_w[0];

    // XCD-bijective swizzle (512 blocks = 64/XCD) + 8x8 supertile per XCD
    const int b = blockIdx.x;
    const int local = b >> 3, chunk = b & 7;         // chunk = XCD id
    const int bm = (chunk & 3) * 8 + (local & 7);    // M/256 = 32
    const int bn = (chunk >> 2) * 8 + (local >> 3);  // N/256 = 16

    const int tid  = threadIdx.x;
    const int wave = tid >> 6;
    const int lane = tid & 63;
    const int wr   = wave >> 2;   // 2 M-waves
    const int wc   = wave & 3;    // 4 N-waves

    // A frag ds_read: row=(lane&31), slot=(lane>>5)*2+h, stored^((row>>1)&3)
    const int sw  = (lane >> 1) & 3;
    const int fo0 = (lane & 31) * 64 + ((((lane >> 5) * 2) + 0 ^ sw)) * 16;
    const int fo1 = (lane & 31) * 64 + ((((lane >> 5) * 2) + 1 ^ sw)) * 16;
    const int wrA = wr * 8192;            // A region: 128 rows per wr

    // A staging: thread tid covers LDS [row=tid>>2][slot=tid&3]; global XOR'd
    const int voff = (tid >> 2) * H_DIM + ((tid & 3) ^ ((tid >> 3) & 3)) * 16;
    const unsigned char* gAlo = A + (size_t)bm * 256 * H_DIM + voff;
    const unsigned char* gAhi = gAlo + (size_t)128 * H_DIM;
    const int tid16 = tid * 16;

    // B direct: lane reads row (wc*64 + n*32 + (lane&31)), k=(lane>>5)*32+[0,32)
    const unsigned char* gB0 =
        B + ((size_t)(bn * 256 + wc * 64 + (lane & 31))) * H_DIM + ((lane >> 5) * 32);
    const unsigned char* gB1 = gB0 + (size_t)32 * H_DIM;

    f32x16 acc[4][2];
#pragma unroll
    for (int m = 0; m < 4; ++m)
#pragma unroll
        for (int n = 0; n < 2; ++n)
#pragma unroll
            for (int e = 0; e < 16; ++e) acc[m][n][e] = 0.0f;

    i32x8 fa[4];
    i32x4 rXa, rXb, rYa, rYb;
    i32x8 bX0, bX1, bY0, bY1;
    int kt2, ktb;

    // prologue: A(0)->rX, B(0)->bX, A(1)->rY; write A(0)->buf0; read frags
    rXa = *(const i32x4*)(gAlo);
    rXb = *(const i32x4*)(gAhi);
    bX0 = *(const i32x8*)(gB0);
    bX1 = *(const i32x8*)(gB1);
    rYa = *(const i32x4*)(gAlo + 64);
    rYb = *(const i32x4*)(gAhi + 64);
    *(i32x4*)(lds + tid16)        = rXa;
    *(i32x4*)(lds + 8192 + tid16) = rXb;
    LGKM0B;
    RDA(0, 0); RDA(0, 1); RDA(0, 2); RDA(0, 3);
    kt2 = 128;   // next A gload: tile 2
    ktb = 64;    // next B gload: tile 1

    // t = 0..61 (31 x 2-unrolled); buf(t+1): t even -> 16384, t odd -> 0
#pragma unroll 1
    for (int it = 0; it < 31; ++it) {
        AITER(rYa, rYb, rXa, rXb, X, Y, 16384);   // even t
        AITER(rXa, rXb, rYa, rYb, Y, X, 0);       // odd t
    }
    // t = 62: write A(63)=rY -> buf1; load B(63)->bY; compute tile62 (bX)
    bY0 = *(const i32x8*)(gB0 + ktb);
    bY1 = *(const i32x8*)(gB1 + ktb);
    *(i32x4*)(lds + 16384 + tid16)        = rYa;
    *(i32x4*)(lds + 16384 + 8192 + tid16) = rYb;
    LGKM0B;
    __builtin_amdgcn_s_setprio(1); MM2(0, X); MM2(1, X);
    __builtin_amdgcn_s_setprio(0);
    RDA(16384, 0); RDA(16384, 1);
    __builtin_amdgcn_s_setprio(1); MM2(2, X); MM2(3, X);
    __builtin_amdgcn_s_setprio(0);
    RDA(16384, 2); RDA(16384, 3);
    // t = 63
    MM2(0, Y); MM2(1, Y); MM2(2, Y); MM2(3, Y);

    // epilogue: C += acc*alpha
    // (32x32 C/D: col = lane&31, row = (e&3) + 8*(e>>2) + 4*(lane>>5))
    const int lrow0 = bm * 256 + wr * 128 + 4 * (lane >> 5);
    const int lcol0 = bn * 256 + wc * 64 + (lane & 31);
#pragma unroll
    for (int m = 0; m < 4; ++m) {
#pragma unroll
        for (int n = 0; n < 2; ++n) {
#pragma unroll
            for (int e = 0; e < 16; ++e) {
                const int row = lrow0 + m * 32 + (e & 3) + 8 * (e >> 2);
                float* cp = C + (size_t)row * H_DIM + lcol0 + n * 32;
                *cp = acc[m][n][e] * alpha + *cp;
            }
        }
    }
}

extern "C" void kernel_launch(void* const* d_in, const int* in_sizes, int n_in,
                              void* d_out, int out_size, void* d_ws, size_t ws_size,
                              hipStream_t stream) {
    const float* h   = (const float*)d_in[0];   // [8192,4096]
    const float* nw  = (const float*)d_in[1];   // [4,4096]
    const float* w   = (const float*)d_in[2];   // [3,4096,4096]
    const float* wsc = (const float*)d_in[3];   // [3]
    const float* sc  = (const float*)d_in[4];   // [3]
    float* out = (float*)d_out;

    unsigned char* wqT = (unsigned char*)d_ws;                       // 3*16M fp8
    unsigned char* qx  = wqT + (size_t)3 * H_DIM * H_DIM;            // 33.5M fp8
    float* resid = (float*)(qx + (size_t)T_DIM * H_DIM);             // 134M f32

    const size_t WSTRIDE = (size_t)H_DIM * H_DIM;

    wquant_kernel<<<dim3(64, 64, 3), 256, 0, stream>>>(w, wqT);

    row_kernel<0><<<T_DIM, 256, 0, stream>>>(h, resid, qx, nw + 0 * H_DIM, sc + 0);
    gemm_fp8_kernel<<<512, 512, 0, stream>>>(qx, wqT + 0 * WSTRIDE, resid, sc + 0, wsc + 0);

    row_kernel<1><<<T_DIM, 256, 0, stream>>>(resid, nullptr, qx, nw + 1 * H_DIM, sc + 1);
    gemm_fp8_kernel<<<512, 512, 0, stream>>>(qx, wqT + 1 * WSTRIDE, resid, sc + 1, wsc + 1);

    row_kernel<1><<<T_DIM, 256, 0, stream>>>(resid, nullptr, qx, nw + 2 * H_DIM, sc + 2);
    gemm_fp8_kernel<<<512, 512, 0, stream>>>(qx, wqT + 2 * WSTRIDE, resid, sc + 2, wsc + 2);

    row_kernel<2><<<T_DIM, 256, 0, stream>>>(resid, nullptr, out, nw + 3 * H_DIM, nullptr);
}

// Round 9
// 666.579 us; speedup vs baseline: 11.0670x; 1.2187x over previous
//
#include <hip/hip_runtime.h>

typedef float f32x4  __attribute__((ext_vector_type(4)));
typedef float f32x16 __attribute__((ext_vector_type(16)));
typedef int   i32x4  __attribute__((ext_vector_type(4)));
typedef int   i32x8  __attribute__((ext_vector_type(8)));

#define T_DIM 8192
#define H_DIM 4096
#define SC1 0x7f7f7f7f   // e8m0 scale = 127 -> 2^0 = 1.0 in all 4 bytes

__device__ __forceinline__ unsigned int pack_fp8x4(float a, float b, float c, float d) {
    int v = __builtin_amdgcn_cvt_pk_fp8_f32(a, b, 0, false);
    v = __builtin_amdgcn_cvt_pk_fp8_f32(c, d, v, true);
    return (unsigned int)v;
}

// ---------------------------------------------------------------------------
// qx (A): PLAIN row-major [row][k]; reg-staged into LDS with XOR slot swizzle
//   slot' = slot ^ ((row>>1)&3) on the GLOBAL source address (LDS linear);
//   ds_read applies the same XOR -> conflict-free b128.
// wqT (B): FRAG-MAJOR: addr = ((((l*16+bn)*64+kt)*4+wc)*2+n2)*2048 + lane*32 + byte
//   where lane = ((k>>5)&1)*32 + (n&31), byte = k&31, bn=n>>8, wc=(n>>6)&3,
//   n2=(n>>5)&1, kt=k>>6.  A wave's B-frag load is then ONE coalesced 2KB
//   read at base + lane*32 (fixes r8's 4KB-strided 64-line-per-instr loads).
// ---------------------------------------------------------------------------

// w[l][k][n] f32  ->  wqT[l] frag-major fp8(e4m3)
__global__ __launch_bounds__(256) void wquant_kernel(
    const float* __restrict__ w, unsigned char* __restrict__ wqT)
{
    const int l  = blockIdx.z;
    const int n0 = blockIdx.x * 64;
    const int k0 = blockIdx.y * 64;
    const int tid = threadIdx.x;
    __shared__ unsigned char tile[64][68];   // [k][n]
    const float* wl = w + (size_t)l * H_DIM * H_DIM;
#pragma unroll
    for (int p = 0; p < 4; ++p) {
        int r = p * 16 + (tid >> 4);         // k within tile
        int c = (tid & 15) * 4;              // n within tile
        f32x4 v = *(const f32x4*)(wl + (size_t)(k0 + r) * H_DIM + n0 + c);
        *(unsigned int*)&tile[r][c] = pack_fp8x4(v[0], v[1], v[2], v[3]);
    }
    __syncthreads();
    const int nl = tid >> 2;                 // n within tile
    const int g  = tid & 3;                  // 16B k-chunk within 64
    unsigned int words[4];
#pragma unroll
    for (int wi = 0; wi < 4; ++wi) {
        unsigned int a = 0;
#pragma unroll
        for (int b = 0; b < 4; ++b)
            a |= (unsigned int)tile[g * 16 + wi * 4 + b][nl] << (8 * b);
        words[wi] = a;
    }
    // frag-major address
    const int bn = n0 >> 8, wc = (n0 >> 6) & 3, kt = k0 >> 6;
    const int n2 = nl >> 5;
    const int lane = (g >> 1) * 32 + (nl & 31);
    const int byte0 = (g & 1) * 16;
    const size_t off = ((((size_t)l * 16 + bn) * 64 + kt) * 4 + wc) * 2 + n2;
    unsigned char* op = wqT + off * 2048 + lane * 32 + byte0;
    uint4 ov; ov.x = words[0]; ov.y = words[1]; ov.z = words[2]; ov.w = words[3];
    *(uint4*)op = ov;
}

// ---------------- row-wise RMSNorm (+relu) (+quant) ----------------
template <int MODE>
__global__ __launch_bounds__(256) void row_kernel(
    const float* __restrict__ in,
    float* __restrict__ resid_out,
    void* __restrict__ out,
    const float* __restrict__ g,
    const float* __restrict__ scale_p)
{
    const int row = blockIdx.x;
    const int tid = threadIdx.x;
    const float* rin = in + (size_t)row * H_DIM;
    float x[16];
    float ss = 0.0f;
#pragma unroll
    for (int j = 0; j < 4; ++j) {
        const int base = (j * 256 + tid) * 4;
        f32x4 v = *(const f32x4*)(rin + base);
        f32x4 rv;
#pragma unroll
        for (int i = 0; i < 4; ++i) {
            float t = v[i];
            if (MODE == 0) t = fmaxf(t, 0.0f);
            x[j * 4 + i] = t;
            rv[i] = t;
            ss += t * t;
        }
        if (MODE == 0)
            *(f32x4*)(resid_out + (size_t)row * H_DIM + base) = rv;
    }
#pragma unroll
    for (int off = 32; off > 0; off >>= 1)
        ss += __shfl_down(ss, off, 64);
    __shared__ float red[4];
    if ((tid & 63) == 0) red[tid >> 6] = ss;
    __syncthreads();
    const float var  = (red[0] + red[1] + red[2] + red[3]) * (1.0f / (float)H_DIM);
    const float rinv = 1.0f / sqrtf(var + 1e-6f);

    if (MODE == 2) {
        float* ro = (float*)out + (size_t)row * H_DIM;
#pragma unroll
        for (int j = 0; j < 4; ++j) {
            const int base = (j * 256 + tid) * 4;
            f32x4 gv = *(const f32x4*)(g + base);
            f32x4 ov;
#pragma unroll
            for (int i = 0; i < 4; ++i) ov[i] = (x[j * 4 + i] * rinv) * gv[i];
            *(f32x4*)(ro + base) = ov;
        }
    } else {
        const float s = scale_p[0];
        unsigned int* qo = (unsigned int*)out + (size_t)row * (H_DIM / 4);
#pragma unroll
        for (int j = 0; j < 4; ++j) {
            const int base = (j * 256 + tid) * 4;
            f32x4 gv = *(const f32x4*)(g + base);
            float q[4];
#pragma unroll
            for (int i = 0; i < 4; ++i) {
                float y = (x[j * 4 + i] * rinv) * gv[i];
                y = y / s;
                q[i] = fminf(fmaxf(y, -448.0f), 448.0f);
            }
            qo[j * 256 + tid] = pack_fp8x4(q[0], q[1], q[2], q[3]);
        }
    }
}

// ---- MX-fp8 GEMM, 256x256 tile, BK=64, A reg-staged 2-buf LDS, B direct ----
#define LGKM0B do { asm volatile("s_waitcnt lgkmcnt(0)" ::: "memory"); \
                    __builtin_amdgcn_s_barrier(); } while (0)

#define MM2(m, P) do {                                                          \
    acc[m][0] = __builtin_amdgcn_mfma_scale_f32_32x32x64_f8f6f4(                \
        fa[m], b##P##0, acc[m][0], 0, 0, 0, SC1, 0, SC1);                       \
    acc[m][1] = __builtin_amdgcn_mfma_scale_f32_32x32x64_f8f6f4(                \
        fa[m], b##P##1, acc[m][1], 0, 0, 0, SC1, 0, SC1);                       \
} while (0)

#define RDA(ORQ, m) do {                                                        \
    *(i32x4*)&fa[m]         = *(const i32x4*)(lds + (ORQ) + wrA + (m) * 2048 + fo0); \
    *(((i32x4*)&fa[m]) + 1) = *(const i32x4*)(lds + (ORQ) + wrA + (m) * 2048 + fo1); \
} while (0)

// iter t: gload A(t+2)->LD regs, gload B(t+1)->FN regs (coalesced frag-major),
// ds_write A(t+1)=WR regs -> buf BUF, fence+barrier, MFMA(t) with FC
// interleaved with ds_read of tile t+1 frags from BUF.
#define AITER(WRa, WRb, LDa, LDb, FC, FN, BUF) do {                             \
    LDa = *(const i32x4*)(gAlo + kt2);                                          \
    LDb = *(const i32x4*)(gAhi + kt2);                                          \
    kt2 += 64;                                                                  \
    b##FN##0 = *(const i32x8*)(gB0 + ktb);                                      \
    b##FN##1 = *(const i32x8*)(gB0 + ktb + 2048);                               \
    ktb += 16384;                                                               \
    *(i32x4*)(lds + (BUF) + tid16)        = WRa;                                \
    *(i32x4*)(lds + (BUF) + 8192 + tid16) = WRb;                                \
    LGKM0B;                                                                     \
    __builtin_amdgcn_s_setprio(1); MM2(0, FC); MM2(1, FC);                      \
    __builtin_amdgcn_s_setprio(0);                                              \
    RDA(BUF, 0); RDA(BUF, 1);                                                   \
    __builtin_amdgcn_s_setprio(1); MM2(2, FC); MM2(3, FC);                      \
    __builtin_amdgcn_s_setprio(0);                                              \
    RDA(BUF, 2); RDA(BUF, 3);                                                   \
} while (0)

__global__ __launch_bounds__(512, 2) void gemm_fp8_kernel(
    const unsigned char* __restrict__ A,
    const unsigned char* __restrict__ B,
    float* __restrict__ C,
    const float* __restrict__ s_in,
    const float* __restrict__ s_w)
{
    __shared__ unsigned char lds[32768];   // 2 bufs x 16K (A only)

    const float alpha = s_in[0] * s_w[0];

    // XCD-bijective swizzle (512 blocks = 64/XCD) + 8x8 supertile per XCD
    const int b = blockIdx.x;
    const int local = b >> 3, chunk = b & 7;         // chunk = XCD id
    const int bm = (chunk & 3) * 8 + (local & 7);    // M/256 = 32
    const int bn = (chunk >> 2) * 8 + (local >> 3);  // N/256 = 16

    const int tid  = threadIdx.x;
    const int wave = tid >> 6;
    const int lane = tid & 63;
    const int wr   = wave >> 2;   // 2 M-waves
    const int wc   = wave & 3;    // 4 N-waves

    // A frag ds_read: row=(lane&31), slot=(lane>>5)*2+h, stored^((row>>1)&3)
    const int sw  = (lane >> 1) & 3;
    const int fo0 = (lane & 31) * 64 + ((((lane >> 5) * 2) + 0 ^ sw)) * 16;
    const int fo1 = (lane & 31) * 64 + ((((lane >> 5) * 2) + 1 ^ sw)) * 16;
    const int wrA = wr * 8192;            // A region: 128 rows per wr

    // A staging: thread tid covers LDS [row=tid>>2][slot=tid&3]; global XOR'd
    const int voff = (tid >> 2) * H_DIM + ((tid & 3) ^ ((tid >> 3) & 3)) * 16;
    const unsigned char* gAlo = A + (size_t)bm * 256 * H_DIM + voff;
    const unsigned char* gAhi = gAlo + (size_t)128 * H_DIM;
    const int tid16 = tid * 16;

    // B frag-major: base for (bn, kt=0, wc, n2=0) + lane*32; coalesced 2KB/wave
    const unsigned char* gB0 =
        B + ((((size_t)bn * 64) * 4 + wc) * 2) * 2048 + lane * 32;

    f32x16 acc[4][2];
#pragma unroll
    for (int m = 0; m < 4; ++m)
#pragma unroll
        for (int n = 0; n < 2; ++n)
#pragma unroll
            for (int e = 0; e < 16; ++e) acc[m][n][e] = 0.0f;

    i32x8 fa[4];
    i32x4 rXa, rXb, rYa, rYb;
    i32x8 bX0, bX1, bY0, bY1;
    int kt2, ktb;

    // prologue: A(0)->rX, B(0)->bX, A(1)->rY; write A(0)->buf0; read frags
    rXa = *(const i32x4*)(gAlo);
    rXb = *(const i32x4*)(gAhi);
    bX0 = *(const i32x8*)(gB0);
    bX1 = *(const i32x8*)(gB0 + 2048);
    rYa = *(const i32x4*)(gAlo + 64);
    rYb = *(const i32x4*)(gAhi + 64);
    *(i32x4*)(lds + tid16)        = rXa;
    *(i32x4*)(lds + 8192 + tid16) = rXb;
    LGKM0B;
    RDA(0, 0); RDA(0, 1); RDA(0, 2); RDA(0, 3);
    kt2 = 128;     // next A gload: tile 2 (plain layout, 64B/tile)
    ktb = 16384;   // next B gload: tile 1 (frag-major, 16KB/tile)

    // t = 0..61 (31 x 2-unrolled); buf(t+1): t even -> 16384, t odd -> 0
#pragma unroll 1
    for (int it = 0; it < 31; ++it) {
        AITER(rYa, rYb, rXa, rXb, X, Y, 16384);   // even t
        AITER(rXa, rXb, rYa, rYb, Y, X, 0);       // odd t
    }
    // t = 62: write A(63)=rY -> buf1; load B(63)->bY; compute tile62 (bX)
    bY0 = *(const i32x8*)(gB0 + ktb);
    bY1 = *(const i32x8*)(gB0 + ktb + 2048);
    *(i32x4*)(lds + 16384 + tid16)        = rYa;
    *(i32x4*)(lds + 16384 + 8192 + tid16) = rYb;
    LGKM0B;
    __builtin_amdgcn_s_setprio(1); MM2(0, X); MM2(1, X);
    __builtin_amdgcn_s_setprio(0);
    RDA(16384, 0); RDA(16384, 1);
    __builtin_amdgcn_s_setprio(1); MM2(2, X); MM2(3, X);
    __builtin_amdgcn_s_setprio(0);
    RDA(16384, 2); RDA(16384, 3);
    // t = 63
    MM2(0, Y); MM2(1, Y); MM2(2, Y); MM2(3, Y);

    // epilogue: C += acc*alpha
    // (32x32 C/D: col = lane&31, row = (e&3) + 8*(e>>2) + 4*(lane>>5))
    const int lrow0 = bm * 256 + wr * 128 + 4 * (lane >> 5);
    const int lcol0 = bn * 256 + wc * 64 + (lane & 31);
#pragma unroll
    for (int m = 0; m < 4; ++m) {
#pragma unroll
        for (int n = 0; n < 2; ++n) {
#pragma unroll
            for (int e = 0; e < 16; ++e) {
                const int row = lrow0 + m * 32 + (e & 3) + 8 * (e >> 2);
                float* cp = C + (size_t)row * H_DIM + lcol0 + n * 32;
                *cp = acc[m][n][e] * alpha + *cp;
            }
        }
    }
}

extern "C" void kernel_launch(void* const* d_in, const int* in_sizes, int n_in,
                              void* d_out, int out_size, void* d_ws, size_t ws_size,
                              hipStream_t stream) {
    const float* h   = (const float*)d_in[0];   // [8192,4096]
    const float* nw  = (const float*)d_in[1];   // [4,4096]
    const float* w   = (const float*)d_in[2];   // [3,4096,4096]
    const float* wsc = (const float*)d_in[3];   // [3]
    const float* sc  = (const float*)d_in[4];   // [3]
    float* out = (float*)d_out;

    unsigned char* wqT = (unsigned char*)d_ws;                       // 3*16M fp8
    unsigned char* qx  = wqT + (size_t)3 * H_DIM * H_DIM;            // 33.5M fp8
    float* resid = (float*)(qx + (size_t)T_DIM * H_DIM);             // 134M f32

    const size_t WSTRIDE = (size_t)H_DIM * H_DIM;

    wquant_kernel<<<dim3(64, 64, 3), 256, 0, stream>>>(w, wqT);

    row_kernel<0><<<T_DIM, 256, 0, stream>>>(h, resid, qx, nw + 0 * H_DIM, sc + 0);
    gemm_fp8_kernel<<<512, 512, 0, stream>>>(qx, wqT + 0 * WSTRIDE, resid, sc + 0, wsc + 0);

    row_kernel<1><<<T_DIM, 256, 0, stream>>>(resid, nullptr, qx, nw + 1 * H_DIM, sc + 1);
    gemm_fp8_kernel<<<512, 512, 0, stream>>>(qx, wqT + 1 * WSTRIDE, resid, sc + 1, wsc + 1);

    row_kernel<1><<<T_DIM, 256, 0, stream>>>(resid, nullptr, qx, nw + 2 * H_DIM, sc + 2);
    gemm_fp8_kernel<<<512, 512, 0, stream>>>(qx, wqT + 2 * WSTRIDE, resid, sc + 2, wsc + 2);

    row_kernel<2><<<T_DIM, 256, 0, stream>>>(resid, nullptr, out, nw + 3 * H_DIM, nullptr);
}